// Round 4
// baseline (68.004 us; speedup 1.0000x reference)
//
#include <hip/hip_runtime.h>

#define M_AG   4608
#define NPO    1536
#define D_DIM  256
#define H_DIM  512
#define NBIG   1536
#define GRID_SZ 256
#define NB_CAP 48

typedef __attribute__((ext_vector_type(8))) short short8;
typedef __attribute__((ext_vector_type(4))) float f32x4;
typedef unsigned short ushort_t;

__device__ __forceinline__ ushort_t f2bf(float f) {
  unsigned int u = __builtin_bit_cast(unsigned int, f);
  unsigned int r = (u + 0x7FFFu + ((u >> 16) & 1u)) >> 16;   // RNE, finite inputs
  return (ushort_t)r;
}
__device__ __forceinline__ float bf2f(ushort_t u) {
  return __builtin_bit_cast(float, (unsigned int)u << 16);
}
__device__ __forceinline__ float tanh_fast(float x) {
  float e = __builtin_amdgcn_exp2f(x * 2.8853900817779268f);  // exp(2x)
  return 1.f - 2.f * __builtin_amdgcn_rcpf(e + 1.f);
}
// LDS-drain barrier WITHOUT vmcnt(0): prefetch global loads stay in flight.
#define DRAIN_BAR() asm volatile("s_waitcnt lgkmcnt(0)\n\ts_barrier" ::: "memory")

#define GA_GEMM 1728   // 24 n-tiles x 72 m-tiles, 64x64, K=256
#define GA_SCAN 576    // 8 agents/block
#define GB_GEMM 576    // 4 n-tiles x 144 m-tiles, 32x64, K=512

// ---------------------------------------------------------------------------
// Kernel A:
//  blocks [0,1728): [A|B|H1](row-major bf16, cols 0-511|512-1023|1024-1535)
//    = tanh(S*[W_out|W_in|W1]+bias). Reg-staged fp32->bf16, dbuf LDS,
//    single lgkm-drain barrier per K-step, loads for s+1 issued pre-barrier.
//  blocks [1728,2304): neighbor scan, wave/agent x2, ballot-ordered list.
// ---------------------------------------------------------------------------
__global__ __launch_bounds__(256) void fused_a(
    const float* __restrict__ S, const float* __restrict__ W_out,
    const float* __restrict__ W_in, const float* __restrict__ W1,
    const float* __restrict__ b_out, const float* __restrict__ b_in,
    const float* __restrict__ b1,
    const int* __restrict__ roles, const int* __restrict__ positions,
    ushort_t* __restrict__ ABH, int4* __restrict__ stats, int* __restrict__ nb)
{
  __shared__ __align__(16) char smem[32768];
  const int b = blockIdx.x, t = threadIdx.x;

  if (b < GA_GEMM) {
    ushort_t* base = (ushort_t*)smem;   // [p][A 4096 | B 4096] ushort
    const int bx = b % 24, by = b / 24;
    const int n0 = bx * 64, m0 = by * 64;
    const int org = m0 / NPO;
    const int which = n0 >> 9;
    const int nlb = n0 & 511;
    const float* __restrict__ Wsel =
        (which == 0 ? W_out : which == 1 ? W_in : W1) + (size_t)org * D_DIM * H_DIM;
    const int rc = t & 63;          // row (A) / col (B)
    const int ga = t >> 6;          // g in {ga, ga+4} of 8 kgroups
    const int w = t >> 6, l = t & 63;
    const int wm = w >> 1, wn = w & 1;
    const int lr = l & 15, lg = l >> 4;

    f32x4 acc[2][2] = {};
    float ra[2][8], rb[2][8];

    auto LOADS = [&](int s) {
      const int k0 = s * 64;
#pragma unroll
      for (int gi = 0; gi < 2; ++gi) {
        const int g = ga + gi * 4;
        const float* ps = S + (size_t)(m0 + rc) * D_DIM + k0 + g * 8;
        float4 v0 = *(const float4*)ps;
        float4 v1 = *(const float4*)(ps + 4);
        ra[gi][0] = v0.x; ra[gi][1] = v0.y; ra[gi][2] = v0.z; ra[gi][3] = v0.w;
        ra[gi][4] = v1.x; ra[gi][5] = v1.y; ra[gi][6] = v1.z; ra[gi][7] = v1.w;
        const float* pw = Wsel + (size_t)(k0 + g * 8) * H_DIM + nlb + rc;
#pragma unroll
        for (int j = 0; j < 8; ++j) rb[gi][j] = pw[(size_t)j * H_DIM];
      }
    };

    LOADS(0);
    int p = 0;
    for (int s = 0; s < 4; ++s) {
      ushort_t* Ab = base + p * 8192;
      ushort_t* Bb = Ab + 4096;
#pragma unroll
      for (int gi = 0; gi < 2; ++gi) {
        short8 va, vb;
#pragma unroll
        for (int j = 0; j < 8; ++j) {
          va[j] = (short)f2bf(ra[gi][j]);
          vb[j] = (short)f2bf(rb[gi][j]);
        }
        *(short8*)(Ab + ((size_t)(ga + gi * 4) * 64 + rc) * 8) = va;
        *(short8*)(Bb + ((size_t)(ga + gi * 4) * 64 + rc) * 8) = vb;
      }
      if (s < 3) LOADS(s + 1);        // in flight across the barrier
      DRAIN_BAR();
      const short8* Ap = (const short8*)Ab;
      const short8* Bp = (const short8*)Bb;
      short8 af[2][2], bf_[2][2];
#pragma unroll
      for (int ks = 0; ks < 2; ++ks) {
#pragma unroll
        for (int mi = 0; mi < 2; ++mi)
          af[mi][ks] = Ap[(ks * 4 + lg) * 64 + wm * 32 + mi * 16 + lr];
#pragma unroll
        for (int ni = 0; ni < 2; ++ni)
          bf_[ni][ks] = Bp[(ks * 4 + lg) * 64 + wn * 32 + ni * 16 + lr];
      }
#pragma unroll
      for (int mi = 0; mi < 2; ++mi)
#pragma unroll
        for (int ni = 0; ni < 2; ++ni)
#pragma unroll
          for (int ks = 0; ks < 2; ++ks)
            acc[mi][ni] = __builtin_amdgcn_mfma_f32_16x16x32_bf16(
                af[mi][ks], bf_[ni][ks], acc[mi][ni], 0, 0, 0);
      p ^= 1;
    }

    const float* bias = (which == 0 ? b_out : which == 1 ? b_in : b1) + (size_t)org * H_DIM;
#pragma unroll
    for (int ni = 0; ni < 2; ++ni) {
      const int nl = nlb + wn * 32 + ni * 16 + lr;
      const float bb = bias[nl];
      const int col = which * 512 + nl;
#pragma unroll
      for (int mi = 0; mi < 2; ++mi)
#pragma unroll
        for (int r = 0; r < 4; ++r) {
          const int row = m0 + wm * 32 + mi * 16 + lg * 4 + r;
          ABH[(size_t)row * NBIG + col] = f2bf(tanh_fast(acc[mi][ni][r] + bb));
        }
    }
  } else {
    // ---------------- neighbor scan ----------------
    int* pk = (int*)smem;   // x | y<<8 | role<<16
    for (int j = t; j < M_AG; j += 256) {
      int2 p2 = ((const int2*)positions)[j];
      pk[j] = p2.x | (p2.y << 8) | (roles[j] << 16);
    }
    __syncthreads();
    const int w = t >> 6, l = t & 63;
    const int base_i = (b - GA_GEMM) * 8;
#pragma unroll
    for (int rep = 0; rep < 2; ++rep) {
      const int i = base_i + rep * 4 + w;
      const int pi = pk[i];
      const int xi = pi & 255, yi = (pi >> 8) & 255;
      const int my_org = (i >= NPO) + (i >= 2 * NPO);  // org_ids = repeat(arange(3),1536)
      int nbn = 0, c_mass = 0, c_fi = 0, c_enemy = 0;
      for (int bs = 0; bs < M_AG; bs += 64) {
        int j = bs + l;
        int pj = pk[j];
        int dx = (pj & 255) - xi, dy = ((pj >> 8) & 255) - yi;
        int rj = pj >> 16;
        bool in_r = (dx * dx + dy * dy <= 25) && (j != i);
        int oj = (j >= NPO) + (j >= 2 * NPO);
        bool same = in_r && (oj == my_org);
        unsigned long long ms = __ballot(same);
        if (same) {
          int slot = nbn + __popcll(ms & ((1ull << l) - 1ull));
          if (slot < NB_CAP) nb[i * NB_CAP + slot] = j;   // ascending j order
        }
        nbn     += __popcll(ms);
        c_mass  += __popcll(__ballot(same && rj == 0));
        c_fi    += __popcll(__ballot(same && rj == 1));
        c_enemy += __popcll(__ballot(in_r && (oj != my_org) && rj == 1));
      }
      if (l == 0) stats[i] = make_int4(nbn, c_mass, c_fi, c_enemy);
    }
  }
}

// ---------------------------------------------------------------------------
// Kernel B:
//  blocks [0,576): SP = H1*W2 + b2 (32x64 tile, K=512) fused with the states
//    update -> out[row][0:256].
//  blocks [576,1728): per-agent finish (wave/agent): dots + energy/roles.
// ---------------------------------------------------------------------------
__global__ __launch_bounds__(256) void fused_b(
    const ushort_t* __restrict__ ABH, const float* __restrict__ W2,
    const float* __restrict__ b2, const float* __restrict__ states,
    const float* __restrict__ energies, const float* __restrict__ resource_grid,
    const int* __restrict__ roles, const int* __restrict__ positions,
    const int4* __restrict__ stats, const int* __restrict__ nb,
    float* __restrict__ out)
{
  __shared__ __align__(16) ushort_t sm[12288];   // [p][A 2048 | B 4096]
  const int b = blockIdx.x, t = threadIdx.x;
  const int w = t >> 6, l = t & 63;

  if (b < GB_GEMM) {
    const int bx = b & 3, by = b >> 2;
    const int n0 = bx * 64, m0 = by * 32;
    const int org = m0 / NPO;
    const int wm = w >> 1, wn = w & 1;
    const int lr = l & 15, lg = l >> 4;
    const int rowa = t & 31, gaa = t >> 5;   // A: 1 id/thread (8g x 32row)
    const int colb = t & 63, gb = t >> 6;    // B: g in {gb, gb+4}
    const float* __restrict__ W2o = W2 + (size_t)org * H_DIM * D_DIM;

    f32x4 acc[2] = {};
    short8 ra8;
    float rb[2][8];

    auto LOADS = [&](int s) {
      const int k0 = s * 64;
      ra8 = *(const short8*)(ABH + (size_t)(m0 + rowa) * NBIG + 1024 + k0 + gaa * 8);
#pragma unroll
      for (int gi = 0; gi < 2; ++gi) {
        const int g = gb + gi * 4;
        const float* pw = W2o + (size_t)(k0 + g * 8) * D_DIM + n0 + colb;
#pragma unroll
        for (int j = 0; j < 8; ++j) rb[gi][j] = pw[(size_t)j * D_DIM];
      }
    };

    LOADS(0);
    int p = 0;
    for (int s = 0; s < 8; ++s) {
      ushort_t* Ab = sm + p * 6144;
      ushort_t* Bb = Ab + 2048;
      *(short8*)(Ab + ((size_t)gaa * 32 + rowa) * 8) = ra8;
#pragma unroll
      for (int gi = 0; gi < 2; ++gi) {
        short8 vb;
#pragma unroll
        for (int j = 0; j < 8; ++j) vb[j] = (short)f2bf(rb[gi][j]);
        *(short8*)(Bb + ((size_t)(gb + gi * 4) * 64 + colb) * 8) = vb;
      }
      if (s < 7) LOADS(s + 1);
      DRAIN_BAR();
      const short8* Ap = (const short8*)Ab;
      const short8* Bp = (const short8*)Bb;
      short8 af[2], bf_[2][2];
#pragma unroll
      for (int ks = 0; ks < 2; ++ks) {
        af[ks] = Ap[(ks * 4 + lg) * 32 + wm * 16 + lr];
#pragma unroll
        for (int ni = 0; ni < 2; ++ni)
          bf_[ni][ks] = Bp[(ks * 4 + lg) * 64 + wn * 32 + ni * 16 + lr];
      }
#pragma unroll
      for (int ni = 0; ni < 2; ++ni)
#pragma unroll
        for (int ks = 0; ks < 2; ++ks)
          acc[ni] = __builtin_amdgcn_mfma_f32_16x16x32_bf16(af[ks], bf_[ni][ks], acc[ni], 0, 0, 0);
      p ^= 1;
    }
#pragma unroll
    for (int r = 0; r < 4; ++r) {
      const int row = m0 + wm * 16 + lg * 4 + r;
      const bool has = stats[row].x > 0;
#pragma unroll
      for (int ni = 0; ni < 2; ++ni) {
        const int col = n0 + wn * 32 + ni * 16 + lr;
        const float sv = states[(size_t)row * D_DIM + col];
        out[(size_t)row * 261 + col] =
            has ? sv + 0.1f * (acc[ni][r] + b2[org * D_DIM + col]) : sv;
      }
    }
  } else {
    // ---------------- per-agent finish ----------------
    const int i = (b - GB_GEMM) * 4 + w;
    const int4 stv = stats[i];
    const int cnt = stv.x, mass = stv.y, fi = stv.z, enemy = stv.w;
    float po = 0.f, pin = 0.f;
    if (cnt > 0) {
      short8 av = *(const short8*)(ABH + (size_t)i * NBIG + l * 8);
      short8 bv = *(const short8*)(ABH + (size_t)i * NBIG + 512 + l * 8);
      const int nn = cnt < NB_CAP ? cnt : NB_CAP;
      for (int s = 0; s < nn; ++s) {
        const int j = nb[i * NB_CAP + s];
        short8 bj = *(const short8*)(ABH + (size_t)j * NBIG + 512 + l * 8);
        short8 aj = *(const short8*)(ABH + (size_t)j * NBIG + l * 8);
#pragma unroll
        for (int k2 = 0; k2 < 8; ++k2) {
          po  += bf2f((ushort_t)av[k2]) * bf2f((ushort_t)bj[k2]);
          pin += bf2f((ushort_t)bv[k2]) * bf2f((ushort_t)aj[k2]);
        }
      }
#pragma unroll
      for (int m2 = 1; m2 < 64; m2 <<= 1) {
        po  += __shfl_xor(po,  m2, 64);
        pin += __shfl_xor(pin, m2, 64);
      }
    }
    if (l == 0) {
      const float denom = fmaxf((float)cnt, 1.0f);
      const float invs = 0.044194173824159216f;   // 1/sqrt(512)
      const float ni_v = (cnt > 0) ? (po - pin) * invs / denom : 0.f;
      const int2 p2 = ((const int2*)positions)[i];
      const float res = resource_grid[p2.y * GRID_SZ + p2.x];
      const float e = energies[i];
      const int r = roles[i];
      float e_fi   = e + 0.03f * (float)mass + 0.02f * res - 0.04f * (float)enemy - 0.01f;
      float e_mass = e * 0.98f + 0.02f * ((fi > 0) ? 1.f : 0.f) + 0.01f * res - 0.02f * (float)enemy;
      float ne = (r == 1) ? e_fi : e_mass;
      ne = fminf(fmaxf(ne, 0.f), 1.f);
      const bool can_fi = (ne > 0.5f) && (mass >= 2) && (fi == 0) && (enemy == 0);
      const bool loses = (mass < 1) || (ne < 0.15f) || (enemy > fi + 1);
      const int nr = (r == 0) ? (can_fi ? 1 : 0) : ((r == 1) ? (loses ? 0 : 1) : r);
      float* orow = out + (size_t)i * 261;
      orow[256] = ni_v;
      orow[257] = ne;
      orow[258] = (nr == 0) ? 1.f : 0.f;
      orow[259] = (nr == 1) ? 1.f : 0.f;
      orow[260] = (nr == 2) ? 1.f : 0.f;
    }
  }
}

extern "C" void kernel_launch(void* const* d_in, const int* in_sizes, int n_in,
                              void* d_out, int out_size, void* d_ws, size_t ws_size,
                              hipStream_t stream) {
  const float* states        = (const float*)d_in[0];
  const float* energies      = (const float*)d_in[1];
  const float* resource_grid = (const float*)d_in[2];
  const float* W_out         = (const float*)d_in[3];
  const float* b_out         = (const float*)d_in[4];
  const float* W_in          = (const float*)d_in[5];
  const float* b_in          = (const float*)d_in[6];
  const float* W1            = (const float*)d_in[7];
  const float* b1            = (const float*)d_in[8];
  const float* W2            = (const float*)d_in[9];
  const float* b2            = (const float*)d_in[10];
  const int*   roles         = (const int*)d_in[11];
  const int*   positions     = (const int*)d_in[13];
  float*       out           = (float*)d_out;

  char* ws = (char*)d_ws;
  ushort_t* ABH   = (ushort_t*)(ws);              // [4608][1536] bf16 = 14,155,776 B
  int4*     stats = (int4*)    (ws + 14155776);   //     73,728 B
  int*      nbl   = (int*)     (ws + 14229504);   //    884,736 B  -> 15.1 MB total

  fused_a<<<GA_GEMM + GA_SCAN, 256, 0, stream>>>(
      states, W_out, W_in, W1, b_out, b_in, b1, roles, positions, ABH, stats, nbl);
  fused_b<<<GB_GEMM + 1152, 256, 0, stream>>>(
      ABH, W2, b2, states, energies, resource_grid, roles, positions, stats, nbl, out);
}

// Round 5
// 64.358 us; speedup vs baseline: 1.0567x; 1.0567x over previous
//
#include <hip/hip_runtime.h>

#define M_AG   4608
#define NPO    1536
#define D_DIM  256
#define H_DIM  512
#define NBIG   1536
#define GRID_SZ 256
#define NB_CAP 48

typedef __attribute__((ext_vector_type(8))) short short8;
typedef __attribute__((ext_vector_type(4))) float f32x4;
typedef unsigned short ushort_t;

__device__ __forceinline__ ushort_t f2bf(float f) {
  unsigned int u = __builtin_bit_cast(unsigned int, f);
  unsigned int r = (u + 0x7FFFu + ((u >> 16) & 1u)) >> 16;   // RNE, finite inputs
  return (ushort_t)r;
}
__device__ __forceinline__ float bf2f(ushort_t u) {
  return __builtin_bit_cast(float, (unsigned int)u << 16);
}
__device__ __forceinline__ float tanh_fast(float x) {
  float e = __builtin_amdgcn_exp2f(x * 2.8853900817779268f);  // exp(2x)
  return 1.f - 2.f * __builtin_amdgcn_rcpf(e + 1.f);
}
// async global->LDS, 16B/lane; LDS dest = uniform base + lane*16 (proven r3)
__device__ __forceinline__ void gl_lds16(const ushort_t* g, ushort_t* l) {
  __builtin_amdgcn_global_load_lds(
      (const __attribute__((address_space(1))) unsigned int*)g,
      (__attribute__((address_space(3))) unsigned int*)l, 16, 0, 0);
}

#define PS_BLK  576
#define PW_BLK  576
#define PW2_BLK 192
#define SCAN_BLK 576

// ---------------------------------------------------------------------------
// k_prep: pack fp32 -> bf16 chunked layouts + neighbor scan.
//  Sc  [32][4608][8]   chunk(kg,m)  = S[m][kg*8 .. +8]
//  Wc  [3][32][1536][8] chunk(o,kg,n) = Wsel[o][kg*8+j][nl], n->(which,nl)
//  W2c [3][64][256][8]
//  scan: 8 agents/block, wave/agent, ballot-ordered ascending list
// ---------------------------------------------------------------------------
__global__ __launch_bounds__(256) void k_prep(
    const float* __restrict__ S, const float* __restrict__ W_out,
    const float* __restrict__ W_in, const float* __restrict__ W1,
    const float* __restrict__ W2,
    const int* __restrict__ roles, const int* __restrict__ positions,
    ushort_t* __restrict__ Sc, ushort_t* __restrict__ Wc,
    ushort_t* __restrict__ W2c, int4* __restrict__ stats, int* __restrict__ nb)
{
  __shared__ int pk[M_AG];   // x | y<<8 | role<<16
  const int b = blockIdx.x, t = threadIdx.x;

  if (b < PS_BLK) {
    int idx = b * 256 + t;                      // < 32*4608
    int kc = idx / M_AG, m = idx - kc * M_AG;
    const float* p = S + (size_t)m * D_DIM + kc * 8;
    ushort_t* d = Sc + (size_t)idx * 8;
#pragma unroll
    for (int j = 0; j < 8; ++j) d[j] = f2bf(p[j]);
  } else if (b < PS_BLK + PW_BLK) {
    int idx = (b - PS_BLK) * 256 + t;           // < 3*32*1536
    int org = idx / (32 * NBIG);
    int rem = idx - org * (32 * NBIG);
    int kc = rem / NBIG, n = rem - kc * NBIG;
    int which = n >> 9, nl = n & 511;
    const float* Wsel = (which == 0 ? W_out : which == 1 ? W_in : W1);
    const float* p = Wsel + (size_t)org * (D_DIM * H_DIM) + (size_t)kc * 8 * H_DIM + nl;
    ushort_t* d = Wc + (size_t)idx * 8;
#pragma unroll
    for (int j = 0; j < 8; ++j) d[j] = f2bf(p[(size_t)j * H_DIM]);
  } else if (b < PS_BLK + PW_BLK + PW2_BLK) {
    int idx = (b - PS_BLK - PW_BLK) * 256 + t;  // < 3*64*256
    int org = idx / (64 * D_DIM);
    int rem = idx - org * (64 * D_DIM);
    int kc = rem >> 8, n = rem & 255;
    const float* p = W2 + (size_t)org * (H_DIM * D_DIM) + (size_t)kc * 8 * D_DIM + n;
    ushort_t* d = W2c + (size_t)idx * 8;
#pragma unroll
    for (int j = 0; j < 8; ++j) d[j] = f2bf(p[(size_t)j * D_DIM]);
  } else {
    for (int j = t; j < M_AG; j += 256) {
      int2 p2 = ((const int2*)positions)[j];
      pk[j] = p2.x | (p2.y << 8) | (roles[j] << 16);
    }
    __syncthreads();
    const int w = t >> 6, l = t & 63;
    const int base_i = (b - (PS_BLK + PW_BLK + PW2_BLK)) * 8;
#pragma unroll
    for (int rep = 0; rep < 2; ++rep) {
      const int i = base_i + rep * 4 + w;
      const int pi = pk[i];
      const int xi = pi & 255, yi = (pi >> 8) & 255;
      const int my_org = (i >= NPO) + (i >= 2 * NPO);  // org_ids = repeat(arange(3),1536)
      int nbn = 0, c_mass = 0, c_fi = 0, c_enemy = 0;
      for (int bs = 0; bs < M_AG; bs += 64) {
        int j = bs + l;
        int pj = pk[j];
        int dx = (pj & 255) - xi, dy = ((pj >> 8) & 255) - yi;
        int rj = pj >> 16;
        bool in_r = (dx * dx + dy * dy <= 25) && (j != i);
        int oj = (j >= NPO) + (j >= 2 * NPO);
        bool same = in_r && (oj == my_org);
        unsigned long long ms = __ballot(same);
        if (same) {
          int slot = nbn + __popcll(ms & ((1ull << l) - 1ull));
          if (slot < NB_CAP) nb[i * NB_CAP + slot] = j;
        }
        nbn     += __popcll(ms);
        c_mass  += __popcll(__ballot(same && rj == 0));
        c_fi    += __popcll(__ballot(same && rj == 1));
        c_enemy += __popcll(__ballot(in_r && (oj != my_org) && rj == 1));
      }
      if (l == 0) stats[i] = make_int4(nbn, c_mass, c_fi, c_enemy);
    }
  }
}

// ---------------------------------------------------------------------------
// k_gemm: [A|B|H1] = tanh(S*[W_out|W_in|W1] + bias).
// 64x64 tile, BK=64, 1728 blocks, single-buffer LDS, global_load_lds only.
// Per K-step/thread: 4 gl_lds dwordx4; per wave: 8 ds_read_b128 + 8 MFMA.
// ---------------------------------------------------------------------------
__global__ __launch_bounds__(256) void k_gemm(
    const ushort_t* __restrict__ Sc, const ushort_t* __restrict__ Wc,
    const float* __restrict__ b_out, const float* __restrict__ b_in,
    const float* __restrict__ b1,
    ushort_t* __restrict__ Abf, ushort_t* __restrict__ Bbf,
    ushort_t* __restrict__ Hc)
{
  __shared__ ushort_t As[4096], Bs[4096];   // [8 kg][64 row][8] each, 8 KB
  const int t = threadIdx.x;
  const int w = t >> 6, l = t & 63;
  const int wm = w >> 1, wn = w & 1;
  const int lr = l & 15, lg = l >> 4;
  const int bx = blockIdx.x, by = blockIdx.y;
  const int n0 = bx * 64, m0 = by * 64;
  const int org = m0 / NPO;
  const int which = n0 >> 9, nlb = n0 & 511;
  const int g0 = t >> 6, r0 = t & 63;       // chunk c = t     -> (g0, r0)
  const int g1 = 4 + g0;                    // chunk c = t+256 -> (g1, r0)

  f32x4 acc[2][2] = {};
  const short8* Ap = (const short8*)As;
  const short8* Bp = (const short8*)Bs;
  const size_t wbase = (size_t)org * 32;

  for (int ks = 0; ks < 4; ++ks) {
    const int kg = ks * 8;
    __syncthreads();
    gl_lds16(Sc + ((size_t)(kg + g0) * M_AG + m0 + r0) * 8, As + (size_t)t * 8);
    gl_lds16(Sc + ((size_t)(kg + g1) * M_AG + m0 + r0) * 8, As + (size_t)(t + 256) * 8);
    gl_lds16(Wc + ((wbase + kg + g0) * NBIG + n0 + r0) * 8, Bs + (size_t)t * 8);
    gl_lds16(Wc + ((wbase + kg + g1) * NBIG + n0 + r0) * 8, Bs + (size_t)(t + 256) * 8);
    __syncthreads();
    short8 af[2][2], bf_[2][2];
#pragma unroll
    for (int k2 = 0; k2 < 2; ++k2) {
#pragma unroll
      for (int mi = 0; mi < 2; ++mi)
        af[mi][k2] = Ap[(k2 * 4 + lg) * 64 + wm * 32 + mi * 16 + lr];
#pragma unroll
      for (int ni = 0; ni < 2; ++ni)
        bf_[ni][k2] = Bp[(k2 * 4 + lg) * 64 + wn * 32 + ni * 16 + lr];
    }
#pragma unroll
    for (int mi = 0; mi < 2; ++mi)
#pragma unroll
      for (int ni = 0; ni < 2; ++ni)
#pragma unroll
        for (int k2 = 0; k2 < 2; ++k2)
          acc[mi][ni] = __builtin_amdgcn_mfma_f32_16x16x32_bf16(
              af[mi][k2], bf_[ni][k2], acc[mi][ni], 0, 0, 0);
  }

  const float* bias = (which == 0 ? b_out : which == 1 ? b_in : b1) + (size_t)org * H_DIM;
  ushort_t* dst = (which == 0) ? Abf : Bbf;
#pragma unroll
  for (int ni = 0; ni < 2; ++ni) {
    const int nl = nlb + wn * 32 + ni * 16 + lr;
    const float bb = bias[nl];
#pragma unroll
    for (int mi = 0; mi < 2; ++mi)
#pragma unroll
      for (int r = 0; r < 4; ++r) {
        const int row = m0 + wm * 32 + mi * 16 + lg * 4 + r;
        ushort_t hv = f2bf(tanh_fast(acc[mi][ni][r] + bb));
        if (which < 2) dst[(size_t)row * H_DIM + nl] = hv;
        else           Hc[((size_t)(nl >> 3) * M_AG + row) * 8 + (nl & 7)] = hv;
      }
  }
}

// ---------------------------------------------------------------------------
// k_spfin:
//  blocks [0,288): SP = H1*W2 + b2, 64x64 tile, K=512 (8 steps), gl_lds from
//    chunked Hc/W2c; epilogue writes out[row][0:256] = has_nb? s+0.1*SP : s.
//  blocks [288,1440): per-agent finish (wave/agent): dots + energy/roles.
// ---------------------------------------------------------------------------
__global__ __launch_bounds__(256) void k_spfin(
    const ushort_t* __restrict__ Hc, const ushort_t* __restrict__ W2c,
    const float* __restrict__ b2, const float* __restrict__ states,
    const ushort_t* __restrict__ Abf, const ushort_t* __restrict__ Bbf,
    const float* __restrict__ energies, const float* __restrict__ resource_grid,
    const int* __restrict__ roles, const int* __restrict__ positions,
    const int4* __restrict__ stats, const int* __restrict__ nb,
    float* __restrict__ out)
{
  __shared__ ushort_t As[4096], Bs[4096];
  const int b = blockIdx.x, t = threadIdx.x;
  const int w = t >> 6, l = t & 63;

  if (b < 288) {
    const int bx = b & 3, by = b >> 2;
    const int n0 = bx * 64, m0 = by * 64;
    const int org = m0 / NPO;
    const int wm = w >> 1, wn = w & 1;
    const int lr = l & 15, lg = l >> 4;
    const int g0 = t >> 6, r0 = t & 63, g1 = 4 + g0;
    f32x4 acc[2][2] = {};
    const short8* Ap = (const short8*)As;
    const short8* Bp = (const short8*)Bs;
    const size_t w2base = (size_t)org * 64;

    for (int ks = 0; ks < 8; ++ks) {
      const int kg = ks * 8;
      __syncthreads();
      gl_lds16(Hc + ((size_t)(kg + g0) * M_AG + m0 + r0) * 8, As + (size_t)t * 8);
      gl_lds16(Hc + ((size_t)(kg + g1) * M_AG + m0 + r0) * 8, As + (size_t)(t + 256) * 8);
      gl_lds16(W2c + ((w2base + kg + g0) * D_DIM + n0 + r0) * 8, Bs + (size_t)t * 8);
      gl_lds16(W2c + ((w2base + kg + g1) * D_DIM + n0 + r0) * 8, Bs + (size_t)(t + 256) * 8);
      __syncthreads();
      short8 af[2][2], bf_[2][2];
#pragma unroll
      for (int k2 = 0; k2 < 2; ++k2) {
#pragma unroll
        for (int mi = 0; mi < 2; ++mi)
          af[mi][k2] = Ap[(k2 * 4 + lg) * 64 + wm * 32 + mi * 16 + lr];
#pragma unroll
        for (int ni = 0; ni < 2; ++ni)
          bf_[ni][k2] = Bp[(k2 * 4 + lg) * 64 + wn * 32 + ni * 16 + lr];
      }
#pragma unroll
      for (int mi = 0; mi < 2; ++mi)
#pragma unroll
        for (int ni = 0; ni < 2; ++ni)
#pragma unroll
          for (int k2 = 0; k2 < 2; ++k2)
            acc[mi][ni] = __builtin_amdgcn_mfma_f32_16x16x32_bf16(
                af[mi][k2], bf_[ni][k2], acc[mi][ni], 0, 0, 0);
    }
#pragma unroll
    for (int mi = 0; mi < 2; ++mi)
#pragma unroll
      for (int r = 0; r < 4; ++r) {
        const int row = m0 + wm * 32 + mi * 16 + lg * 4 + r;
        const bool has = stats[row].x > 0;
#pragma unroll
        for (int ni = 0; ni < 2; ++ni) {
          const int col = n0 + wn * 32 + ni * 16 + lr;
          const float sv = states[(size_t)row * D_DIM + col];
          out[(size_t)row * 261 + col] =
              has ? sv + 0.1f * (acc[mi][ni][r] + b2[org * D_DIM + col]) : sv;
        }
      }
  } else {
    const int i = (b - 288) * 4 + w;
    const int4 stv = stats[i];
    const int cnt = stv.x, mass = stv.y, fi = stv.z, enemy = stv.w;
    float po = 0.f, pin = 0.f;
    if (cnt > 0) {
      short8 av = *(const short8*)(Abf + (size_t)i * H_DIM + l * 8);
      short8 bv = *(const short8*)(Bbf + (size_t)i * H_DIM + l * 8);
      const int nn = cnt < NB_CAP ? cnt : NB_CAP;
      for (int s = 0; s < nn; ++s) {
        const int j = nb[i * NB_CAP + s];
        short8 bj = *(const short8*)(Bbf + (size_t)j * H_DIM + l * 8);
        short8 aj = *(const short8*)(Abf + (size_t)j * H_DIM + l * 8);
#pragma unroll
        for (int k2 = 0; k2 < 8; ++k2) {
          po  += bf2f((ushort_t)av[k2]) * bf2f((ushort_t)bj[k2]);
          pin += bf2f((ushort_t)bv[k2]) * bf2f((ushort_t)aj[k2]);
        }
      }
#pragma unroll
      for (int m2 = 1; m2 < 64; m2 <<= 1) {
        po  += __shfl_xor(po,  m2, 64);
        pin += __shfl_xor(pin, m2, 64);
      }
    }
    if (l == 0) {
      const float denom = fmaxf((float)cnt, 1.0f);
      const float invs = 0.044194173824159216f;   // 1/sqrt(512)
      const float ni_v = (cnt > 0) ? (po - pin) * invs / denom : 0.f;
      const int2 p2 = ((const int2*)positions)[i];
      const float res = resource_grid[p2.y * GRID_SZ + p2.x];
      const float e = energies[i];
      const int r = roles[i];
      float e_fi   = e + 0.03f * (float)mass + 0.02f * res - 0.04f * (float)enemy - 0.01f;
      float e_mass = e * 0.98f + 0.02f * ((fi > 0) ? 1.f : 0.f) + 0.01f * res - 0.02f * (float)enemy;
      float ne = (r == 1) ? e_fi : e_mass;
      ne = fminf(fmaxf(ne, 0.f), 1.f);
      const bool can_fi = (ne > 0.5f) && (mass >= 2) && (fi == 0) && (enemy == 0);
      const bool loses = (mass < 1) || (ne < 0.15f) || (enemy > fi + 1);
      const int nr = (r == 0) ? (can_fi ? 1 : 0) : ((r == 1) ? (loses ? 0 : 1) : r);
      float* orow = out + (size_t)i * 261;
      orow[256] = ni_v;
      orow[257] = ne;
      orow[258] = (nr == 0) ? 1.f : 0.f;
      orow[259] = (nr == 1) ? 1.f : 0.f;
      orow[260] = (nr == 2) ? 1.f : 0.f;
    }
  }
}

extern "C" void kernel_launch(void* const* d_in, const int* in_sizes, int n_in,
                              void* d_out, int out_size, void* d_ws, size_t ws_size,
                              hipStream_t stream) {
  const float* states        = (const float*)d_in[0];
  const float* energies      = (const float*)d_in[1];
  const float* resource_grid = (const float*)d_in[2];
  const float* W_out         = (const float*)d_in[3];
  const float* b_out         = (const float*)d_in[4];
  const float* W_in          = (const float*)d_in[5];
  const float* b_in          = (const float*)d_in[6];
  const float* W1            = (const float*)d_in[7];
  const float* b1            = (const float*)d_in[8];
  const float* W2            = (const float*)d_in[9];
  const float* b2            = (const float*)d_in[10];
  const int*   roles         = (const int*)d_in[11];
  const int*   positions     = (const int*)d_in[13];
  float*       out           = (float*)d_out;

  char* ws = (char*)d_ws;
  ushort_t* Sc    = (ushort_t*)(ws);              //  2,359,296 B
  ushort_t* Wc    = (ushort_t*)(ws +  2359296);   //  2,359,296 B
  ushort_t* W2c   = (ushort_t*)(ws +  4718592);   //    786,432 B
  ushort_t* Hc    = (ushort_t*)(ws +  5505024);   //  4,718,592 B
  ushort_t* Abf   = (ushort_t*)(ws + 10223616);   //  4,718,592 B
  ushort_t* Bbf   = (ushort_t*)(ws + 14942208);   //  4,718,592 B
  int4*     stats = (int4*)    (ws + 19660800);   //     73,728 B
  int*      nbl   = (int*)     (ws + 19734528);   //    884,736 B  -> 20.6 MB

  k_prep<<<PS_BLK + PW_BLK + PW2_BLK + SCAN_BLK, 256, 0, stream>>>(
      states, W_out, W_in, W1, W2, roles, positions, Sc, Wc, W2c, stats, nbl);
  k_gemm<<<dim3(24, 72), 256, 0, stream>>>(Sc, Wc, b_out, b_in, b1, Abf, Bbf, Hc);
  k_spfin<<<1440, 256, 0, stream>>>(Hc, W2c, b2, states, Abf, Bbf,
                                    energies, resource_grid, roles, positions,
                                    stats, nbl, out);
}